// Round 9
// baseline (7137.102 us; speedup 1.0000x reference)
//
#include <hip/hip_runtime.h>
#include <cmath>

typedef _Float16 f16;
typedef _Float16 f16x8 __attribute__((ext_vector_type(8)));
typedef float f32x4 __attribute__((ext_vector_type(4)));

#define NR 2048
#define NU 80
#define NUP 96          // NU padded to multiple of 32
#define NB 32           // batch
#define NS 1024         // seq len
#define NWG 32          // 32 WGs x 64 output cols
#define ALPHA 0.6f
#define SIGMA_B 1.6f
#define POLL_BOUND (1 << 20)   // escape: deadlock -> bounded, diagnosable wrong answer

#define FLAG_STRIDE 16   // ints (64B per flag)

// workspace layout (bytes)
#define OFF_AF   0ull                              // A fp16 [2048][2048] : 8 MiB
#define OFF_XP   (OFF_AF + (size_t)NR*NR*2)        // input fp16 [s][b][96] : 6 MiB
#define OFF_BP   (OFF_XP + (size_t)NS*NB*NUP*2)    // B fp16 [2048][96]
#define OFF_RB   (OFF_BP + (size_t)NR*NUP*2)       // r bufs fp16 [2][NB][NR] : 256 KiB
#define OFF_FLG  (OFF_RB + (size_t)2*NB*NR*2)      // step flags [NWG][FLAG_STRIDE]
#define ZERO_BYTES ((size_t)NWG*FLAG_STRIDE*4)

__global__ void prep_kernel(const float* __restrict__ input,
                            const float* __restrict__ r0,
                            const float* __restrict__ A,
                            const float* __restrict__ B,
                            f16* __restrict__ Af, f16* __restrict__ xp,
                            f16* __restrict__ Bp, f16* __restrict__ rb)
{
    const int stride = gridDim.x * blockDim.x;
    const int tid = blockIdx.x * blockDim.x + threadIdx.x;
    for (int i = tid; i < NR * NR; i += stride) Af[i] = (f16)A[i];
    for (int i = tid; i < NS * NB * NUP; i += stride) {
        int u = i % NUP; int sb = i / NUP; int b = sb % NB; int s = sb / NB;
        xp[i] = (u < NU) ? (f16)input[((size_t)b * NS + s) * NU + u] : (f16)0.0f;
    }
    for (int i = tid; i < NR * NUP; i += stride) {
        int u = i % NUP; int j = i / NUP;
        Bp[i] = (u < NU) ? (f16)B[j * NU + u] : (f16)0.0f;
    }
    for (int i = tid; i < NB * NR; i += stride) rb[i] = (f16)r0[i];  // buffer 0
}

#define MFMA(va, vb, vc) __builtin_amdgcn_mfma_f32_16x16x32_f16(va, vb, vc, 0, 0, 0)

// Device-scope reservoir scan (all cross-WG traffic via the proven sc0sc1 /
// agent-atomic coherence-point discipline -- the ONLY protocol that has passed;
// XCD-local sc0 refuted in rounds 5-8).
// 32 WGs x 512 threads. WG wg owns output cols [wg*64, wg*64+64) for all 32
// batch rows. Wave w (=K-octant kq) consumes r cols [256w, 256w+256), i.e.
// depends on exactly 4 producer WGs: 4w..4w+3. Wave w also OWNS output combo
// (ct = w&3, rt = w>>2): 16 cols x 16 rows, its master state in registers.
// Per step: poll 4 flags -> 3 xq + 16 r loads (counted vmcnt windows) ->
// 64+3 MFMAs -> LDS partial reduce -> tanh -> register-direct sc publish ->
// ack -> flag. 2 barriers/step.
__global__ __launch_bounds__(512, 2) void scan_kernel(
    float* __restrict__ out,
    const float* __restrict__ r0,
    const f16* __restrict__ Af, const f16* __restrict__ xp,
    const f16* __restrict__ Bp, f16* __restrict__ rbuf,
    int* __restrict__ flags)
{
    const int tid  = threadIdx.x;
    const int lane = tid & 63;
    const int wv   = tid >> 6;      // K-octant AND owned output combo
    const int ct   = wv & 3;        // owned 16-col tile
    const int rt   = wv >> 2;       // owned 16-row tile
    const int wg   = blockIdx.x;
    const int col0 = wg * 64;
    const int fr   = lane & 15;     // fragment row/col
    const int kg   = lane >> 4;     // k-chunk within fragment

    __shared__ f32x4 lds_part[8][8][64];   // [wave][combo][lane]

    // ---- A-slice -> registers (B^T fragment layout): 64 cols x 256 K
    // bf[c][kf] lane l elem j = A[col0 + c*16 + (l&15)][wv*256 + kf*32 + (l>>4)*8 + j]
    f16x8 bf[4][8];
    #pragma unroll
    for (int c = 0; c < 4; ++c) {
        const f16* ab = Af + (size_t)(col0 + c * 16 + fr) * NR + wv * 256 + kg * 8;
        #pragma unroll
        for (int kf = 0; kf < 8; ++kf)
            bf[c][kf] = *(const f16x8*)(ab + kf * 32);
    }
    #pragma unroll
    for (int c = 0; c < 4; ++c)
        #pragma unroll
        for (int kf = 0; kf < 8; ++kf)
            asm volatile("" : "+v"(bf[c][kf]));   // pin: no remat

    // ---- input-projection B fragments for the OWNED combo (K = 96 padded)
    f16x8 bp0, bp1, bp2;
    {
        const f16* bb = Bp + (size_t)(col0 + ct * 16 + fr) * NUP + kg * 8;
        bp0 = *(const f16x8*)(bb);
        bp1 = *(const f16x8*)(bb + 32);
        bp2 = *(const f16x8*)(bb + 64);
        asm volatile("" : "+v"(bp0)); asm volatile("" : "+v"(bp1));
        asm volatile("" : "+v"(bp2));
    }

    // ---- fp32 master state for the owned combo: rows rt*16+kg*4+i, col ct*16+fr
    float rm0, rm1, rm2, rm3;
    {
        const float* rp = r0 + (size_t)(rt * 16 + kg * 4) * NR + col0 + ct * 16 + fr;
        rm0 = rp[0 * NR]; rm1 = rp[1 * NR]; rm2 = rp[2 * NR]; rm3 = rp[3 * NR];
    }

    int* myflag = flags + (size_t)wg * FLAG_STRIDE;
    int* pollp  = flags + (size_t)(wv * 4 + (lane & 3)) * FLAG_STRIDE;

    asm volatile("s_waitcnt vmcnt(0) lgkmcnt(0)" ::: "memory");

    f16x8 xa0,xa1,xa2,xa3,xa4,xa5,xa6,xa7, xb0,xb1,xb2,xb3,xb4,xb5,xb6,xb7;

    for (int s = 0; s < NS; ++s) {
        const f16* cur = rbuf + (size_t)(s & 1) * NB * NR;
        f16*       nxt = rbuf + (size_t)((s + 1) & 1) * NB * NR;

        // ---- poll my 4 producers (one CP round trip checks all)
        if (s) {
            int spins = 0;
            while (true) {
                int v = 0x7fffffff;
                if ((lane & 63) < 4)
                    v = __hip_atomic_load(pollp, __ATOMIC_RELAXED,
                                          __HIP_MEMORY_SCOPE_AGENT);
                if (__all(v >= s)) break;
                if (++spins > POLL_BOUND) break;   // escape: no deadlock
                __builtin_amdgcn_s_sleep(1);
            }
        }

        // ---- xq loads (cached; rows of owned row-tile)
        f16x8 q0, q1, q2;
        {
            const f16* xb = xp + ((size_t)s * NB + rt * 16 + fr) * NUP + kg * 8;
            asm volatile("global_load_dwordx4 %0, %1, off"           : "=v"(q0) : "v"(xb) : "memory");
            asm volatile("global_load_dwordx4 %0, %1, off offset:64" : "=v"(q1) : "v"(xb) : "memory");
            asm volatile("global_load_dwordx4 %0, %1, off offset:128": "=v"(q2) : "v"(xb) : "memory");
        }

        // ---- r fragment loads (device-coherent), 2 row-tiles x 8 k-frags
        const f16* rl0 = cur + (size_t)fr * NR + wv * 256 + kg * 8;
        const f16* rl1 = rl0 + 16 * NR;
        #define LDX(dst, rtp, kf) asm volatile(                                \
            "global_load_dwordx4 %0, %1, off offset:%2 sc0 sc1"                \
            : "=v"(dst) : "v"(rtp), "n"((kf) * 64) : "memory")
        #define WAITV(n) asm volatile("s_waitcnt vmcnt(" #n ")" ::: "memory"); \
            __builtin_amdgcn_sched_barrier(0)

        LDX(xa0, rl0, 0); LDX(xa1, rl1, 0); LDX(xa2, rl0, 1); LDX(xa3, rl1, 1);
        LDX(xa4, rl0, 2); LDX(xa5, rl1, 2); LDX(xa6, rl0, 3); LDX(xa7, rl1, 3);

        // bu projection into dedicated accumulator for the OWNED combo
        f32x4 accbu = {0, 0, 0, 0};
        WAITV(8);        // q0..q2 done (oldest; any stale nt-stores also drain)
        accbu = MFMA(q0, bp0, accbu);
        accbu = MFMA(q1, bp1, accbu);
        accbu = MFMA(q2, bp2, accbu);

        LDX(xb0, rl0, 4); LDX(xb1, rl1, 4); LDX(xb2, rl0, 5); LDX(xb3, rl1, 5);
        LDX(xb4, rl0, 6); LDX(xb5, rl1, 6); LDX(xb6, rl0, 7); LDX(xb7, rl1, 7);

        f32x4 acc[2][4];
        #pragma unroll
        for (int r = 0; r < 2; ++r)
            #pragma unroll
            for (int c = 0; c < 4; ++c)
                acc[r][c] = (f32x4){0, 0, 0, 0};

        WAITV(8);        // xa octet done
        #pragma unroll
        for (int c = 0; c < 4; ++c) {
            acc[0][c] = MFMA(xa0, bf[c][0], acc[0][c]);
            acc[1][c] = MFMA(xa1, bf[c][0], acc[1][c]);
            acc[0][c] = MFMA(xa2, bf[c][1], acc[0][c]);
            acc[1][c] = MFMA(xa3, bf[c][1], acc[1][c]);
            acc[0][c] = MFMA(xa4, bf[c][2], acc[0][c]);
            acc[1][c] = MFMA(xa5, bf[c][2], acc[1][c]);
            acc[0][c] = MFMA(xa6, bf[c][3], acc[0][c]);
            acc[1][c] = MFMA(xa7, bf[c][3], acc[1][c]);
        }
        WAITV(0);        // xb octet done
        #pragma unroll
        for (int c = 0; c < 4; ++c) {
            acc[0][c] = MFMA(xb0, bf[c][4], acc[0][c]);
            acc[1][c] = MFMA(xb1, bf[c][4], acc[1][c]);
            acc[0][c] = MFMA(xb2, bf[c][5], acc[0][c]);
            acc[1][c] = MFMA(xb3, bf[c][5], acc[1][c]);
            acc[0][c] = MFMA(xb4, bf[c][6], acc[0][c]);
            acc[1][c] = MFMA(xb5, bf[c][6], acc[1][c]);
            acc[0][c] = MFMA(xb6, bf[c][7], acc[0][c]);
            acc[1][c] = MFMA(xb7, bf[c][7], acc[1][c]);
        }
        #undef LDX
        #undef WAITV

        // ---- partials to LDS (all 8 combos), barrier, owner-reduce
        #pragma unroll
        for (int r = 0; r < 2; ++r)
            #pragma unroll
            for (int c = 0; c < 4; ++c)
                lds_part[wv][r * 4 + c][lane] = acc[r][c];
        __syncthreads();                              // #1: partials visible

        f32x4 sum = accbu;   // bu term, computed by this combo's owner
        #pragma unroll
        for (int w = 0; w < 8; ++w)
            sum += lds_part[w][wv][lane];

        float rn0 = (1.0f - ALPHA) * rm0 + ALPHA * tanhf(sum[0] + SIGMA_B);
        float rn1 = (1.0f - ALPHA) * rm1 + ALPHA * tanhf(sum[1] + SIGMA_B);
        float rn2 = (1.0f - ALPHA) * rm2 + ALPHA * tanhf(sum[2] + SIGMA_B);
        float rn3 = (1.0f - ALPHA) * rm3 + ALPHA * tanhf(sum[3] + SIGMA_B);
        rm0 = rn0; rm1 = rn1; rm2 = rn2; rm3 = rn3;

        // ---- register-direct device-coherent publish (16x16 tile per wave)
        if (s != NS - 1) {
            f16 h0 = (f16)rn0, h1 = (f16)rn1, h2 = (f16)rn2, h3 = (f16)rn3;
            int b0 = *(unsigned short*)&h0, b1 = *(unsigned short*)&h1;
            int b2 = *(unsigned short*)&h2, b3 = *(unsigned short*)&h3;
            f16* pb = nxt + (size_t)(rt * 16 + kg * 4) * NR + col0 + ct * 16 + fr;
            asm volatile("global_store_short %0, %1, off sc0 sc1" :: "v"(pb + 0 * NR), "v"(b0) : "memory");
            asm volatile("global_store_short %0, %1, off sc0 sc1" :: "v"(pb + 1 * NR), "v"(b1) : "memory");
            asm volatile("global_store_short %0, %1, off sc0 sc1" :: "v"(pb + 2 * NR), "v"(b2) : "memory");
            asm volatile("global_store_short %0, %1, off sc0 sc1" :: "v"(pb + 3 * NR), "v"(b3) : "memory");
            asm volatile("s_waitcnt vmcnt(0)" ::: "memory");   // acked at CP
        }
        __syncthreads();                              // #2: all publishes acked

        if (s != NS - 1 && tid == 0)
            __hip_atomic_store(myflag, s + 1, __ATOMIC_RELAXED,
                               __HIP_MEMORY_SCOPE_AGENT);

        // ---- output stream (off the critical path)
        {
            float* po = out + ((size_t)(rt * 16 + kg * 4) * NS + s) * NR
                        + col0 + ct * 16 + fr;
            asm volatile("global_store_dword %0, %1, off nt" :: "v"(po + 0ull * NS * NR), "v"(rn0) : "memory");
            asm volatile("global_store_dword %0, %1, off nt" :: "v"(po + 1ull * NS * NR), "v"(rn1) : "memory");
            asm volatile("global_store_dword %0, %1, off nt" :: "v"(po + 2ull * NS * NR), "v"(rn2) : "memory");
            asm volatile("global_store_dword %0, %1, off nt" :: "v"(po + 3ull * NS * NR), "v"(rn3) : "memory");
        }
    }

    // ---- final state r_final (1, 32, 2048)
    {
        float* pf = out + (size_t)NB * NS * NR
                    + (size_t)(rt * 16 + kg * 4) * NR + col0 + ct * 16 + fr;
        pf[0 * NR] = rm0; pf[1 * NR] = rm1; pf[2 * NR] = rm2; pf[3 * NR] = rm3;
    }
}

extern "C" void kernel_launch(void* const* d_in, const int* in_sizes, int n_in,
                              void* d_out, int out_size, void* d_ws, size_t ws_size,
                              hipStream_t stream)
{
    const float* input = (const float*)d_in[0];
    const float* r0    = (const float*)d_in[1];
    const float* A     = (const float*)d_in[2];
    const float* B     = (const float*)d_in[3];
    float* out = (float*)d_out;
    char* ws = (char*)d_ws;

    f16* Af  = (f16*)(ws + OFF_AF);
    f16* xp  = (f16*)(ws + OFF_XP);
    f16* Bp  = (f16*)(ws + OFF_BP);
    f16* rb  = (f16*)(ws + OFF_RB);
    int* flg = (int*)(ws + OFF_FLG);

    hipMemsetAsync(flg, 0, ZERO_BYTES, stream);
    prep_kernel<<<2048, 256, 0, stream>>>(input, r0, A, B, Af, xp, Bp, rb);
    scan_kernel<<<NWG, 512, 0, stream>>>(out, r0, Af, xp, Bp, rb, flg);
}